// Round 16
// baseline (463.334 us; speedup 1.0000x reference)
//
#include <hip/hip_runtime.h>

#define HIDN 2048
#define NHEAD 16
#define HD 128
#define SEQ 2048
#define BATCH 2
#define NROWS (BATCH*SEQ)   // 4096

typedef __bf16 bf16_t;
typedef bf16_t bf16x8 __attribute__((ext_vector_type(8)));
typedef float f32x4 __attribute__((ext_vector_type(4)));
typedef unsigned short ushort8 __attribute__((ext_vector_type(8)));

#define AS1 __attribute__((address_space(1)))
#define AS3 __attribute__((address_space(3)))

__device__ __forceinline__ unsigned short f2bf(float x) {
  union { bf16_t b; unsigned short u; } cv; cv.b = (bf16_t)x; return cv.u;
}

#define MFMA16(a,b,c) __builtin_amdgcn_mfma_f32_16x16x32_bf16((a),(b),(c),0,0,0)

__device__ __forceinline__ void gload16(const void* g, void* l) {
  __builtin_amdgcn_global_load_lds((const AS1 void*)g, (AS3 void*)l, 16, 0, 0);
}

// ---------------------------------------------------------------- fused weight transpose+cvt
__global__ __launch_bounds__(256) void transpose_all_kernel(
    const float* __restrict__ Wq, const float* __restrict__ Wk,
    const float* __restrict__ Wv, const float* __restrict__ Wo,
    const float* __restrict__ w1, const float* __restrict__ w3,
    const float* __restrict__ w2, unsigned short* __restrict__ wblk) {
  const int z = blockIdx.z;
  const float* W; unsigned short* dstb; int tmode = 0, half = 0;
  switch (z) {
    case 0: W = Wq; dstb = wblk;                       tmode = 1; break;
    case 1: W = Wk; dstb = wblk + (size_t)2048 * HIDN; tmode = 1; break;
    case 2: W = Wv; dstb = wblk + (size_t)4096 * HIDN; break;
    case 3: W = Wo; dstb = wblk + (size_t)6144 * HIDN; break;
    case 4: W = w1; dstb = wblk + (size_t)8192 * HIDN; tmode = 2; half = 0; break;
    case 5: W = w3; dstb = wblk + (size_t)8192 * HIDN; tmode = 2; half = 1; break;
    default: W = w2; dstb = wblk + (size_t)12288 * HIDN; break;
  }
  __shared__ float t[64][69];
  const int tid = threadIdx.x;
  const int bn = blockIdx.x * 64, bk = blockIdx.y * 64;
  const int lc = (tid & 15) * 4, lrw = tid >> 4;
#pragma unroll
  for (int i = 0; i < 4; ++i) {
    int k = bk + lrw + i * 16;
    float4 v = *(const float4*)(W + (long)k * HIDN + bn + lc);
    t[lrw + i * 16][lc] = v.x; t[lrw + i * 16][lc + 1] = v.y;
    t[lrw + i * 16][lc + 2] = v.z; t[lrw + i * 16][lc + 3] = v.w;
  }
  __syncthreads();
  const int nl = tid >> 2, k0 = (tid & 3) * 16;
  int n = bn + nl;
  int dst;
  if (tmode == 0) dst = n;
  else if (tmode == 1) { int d = n & 127; dst = (n & ~127) | ((d & 63) << 1) | (d >> 6); }
  else dst = (n >> 4) * 32 + half * 16 + (n & 15);
  unsigned short* orow = dstb + (long)dst * HIDN + bk + k0;
#pragma unroll
  for (int j = 0; j < 16; j += 8) {
    ushort8 o;
#pragma unroll
    for (int jj = 0; jj < 8; ++jj) o[jj] = f2bf(t[k0 + j + jj][nl]);
    *(ushort8*)(orow + j) = o;
  }
}

// ---------------------------------------------------------------- rope tables
__global__ void rope_table_kernel(float* __restrict__ cosT, float* __restrict__ sinT) {
  int s = blockIdx.x, d = threadIdx.x;
  float invf = powf(10000.0f, (-2.0f * (float)d) / 128.0f);
  float ang = (float)s * invf;
  cosT[s * 64 + d] = cosf(ang);
  sinT[s * 64 + d] = sinf(ang);
}

// ---------------------------------------------------------------- rmsnorm
__global__ __launch_bounds__(256) void rmsnorm_kernel(
    const float* __restrict__ x, const float* __restrict__ w, unsigned short* __restrict__ out) {
  long row = blockIdx.x;
  const float* xr = x + row * HIDN;
  int c0 = threadIdx.x * 4;
  float4 v0 = *(const float4*)(xr + c0);
  float4 v1 = *(const float4*)(xr + 1024 + c0);
  float s = v0.x*v0.x + v0.y*v0.y + v0.z*v0.z + v0.w*v0.w
          + v1.x*v1.x + v1.y*v1.y + v1.z*v1.z + v1.w*v1.w;
#pragma unroll
  for (int off = 1; off < 64; off <<= 1) s += __shfl_xor(s, off);
  __shared__ float red[4];
  if ((threadIdx.x & 63) == 0) red[threadIdx.x >> 6] = s;
  __syncthreads();
  float tot = red[0] + red[1] + red[2] + red[3];
  float r = 1.0f / sqrtf(tot * (1.0f / (float)HIDN) + 1e-6f);
  float4 w0 = *(const float4*)(w + c0);
  float4 w1 = *(const float4*)(w + 1024 + c0);
  ushort4 o0, o1;
  o0.x = f2bf(v0.x * r * w0.x); o0.y = f2bf(v0.y * r * w0.y);
  o0.z = f2bf(v0.z * r * w0.z); o0.w = f2bf(v0.w * r * w0.w);
  o1.x = f2bf(v1.x * r * w1.x); o1.y = f2bf(v1.y * r * w1.y);
  o1.z = f2bf(v1.z * r * w1.z); o1.w = f2bf(v1.w * r * w1.w);
  *(ushort4*)(out + row * HIDN + c0) = o0;
  *(ushort4*)(out + row * HIDN + 1024 + c0) = o1;
}

// ---------------------------------------------------------------- GEMM 256x256, 8-phase schedule
// MODE 0: QKV+rope (q pre-scaled by 1/sqrt(HD)*log2e); v transposed to p2.
// MODE 1: gate silu-mul.
template <int MODE>
__global__ __launch_bounds__(512, 2) void gemm256_kernel(
    const unsigned short* __restrict__ A, const unsigned short* __restrict__ Bt,
    int nbx,
    void* __restrict__ p0, void* __restrict__ p1, void* __restrict__ p2,
    const float* __restrict__ cosT, const float* __restrict__ sinT) {
  __shared__ unsigned short L[65536];   // [buf2][mat2][half2][128*64]
  const int tid = threadIdx.x;
  const int wave = tid >> 6, lane = tid & 63;
  const int lr = lane & 15, lkg = lane >> 4;
  const int wr = wave >> 2, wc = wave & 3;
  const int x7 = lr & 7;
  const int nwg = (int)gridDim.x;
  const int bid = (int)blockIdx.x;
  const int wg = (bid & 7) * (nwg >> 3) + (bid >> 3);
  const int bx = wg % nbx, by = wg / nbx;
  const long bm = (long)by * 256, bn = (long)bx * 256;
  const int sslot = (lane & 7) ^ (lane >> 3);
  const unsigned short* Ag = A + (bm + wave * 8 + (lane >> 3)) * HIDN + sslot * 8;
  const unsigned short* Bg = Bt + (bn + wave * 8 + (lane >> 3)) * HIDN + sslot * 8;
  const char* Lc = (const char*)L;
  f32x4 acc[8][4] = {};
  bf16x8 af[2][2], bfr[4][2];

#define STG(b, mat, half, tile)                                                   \
  {                                                                               \
    const unsigned short* gsrc = ((mat) ? Bg : Ag) + ((long)(half) * 128) * HIDN + (long)(tile) * 64; \
    unsigned short* ldst = &L[((4 * (b) + 2 * (mat) + (half)) * 8192) + wave * 8 * 64]; \
    gload16(gsrc, ldst);                                                          \
    gload16(gsrc + (long)64 * HIDN, ldst + 4096);                                 \
  }
#define DSRA(b, q)                                                                \
  { _Pragma("unroll") for (int mm = 0; mm < 2; ++mm) {                            \
      int row128 = ((q) * 2 + mm) * 16 + lr;                                      \
      _Pragma("unroll") for (int ks = 0; ks < 2; ++ks) {                          \
        int s = ks * 4 + lkg;                                                     \
        af[mm][ks] = *(const bf16x8*)(Lc + (4 * (b) + wr) * 16384 + row128 * 128 + ((s ^ x7) << 4)); \
      } } }
#define DSRB(b)                                                                   \
  { _Pragma("unroll") for (int n = 0; n < 4; ++n) {                               \
      int row128 = (wc & 1) * 64 + n * 16 + lr;                                   \
      _Pragma("unroll") for (int ks = 0; ks < 2; ++ks) {                          \
        int s = ks * 4 + lkg;                                                     \
        bfr[n][ks] = *(const bf16x8*)(Lc + (4 * (b) + 2 + (wc >> 1)) * 16384 + row128 * 128 + ((s ^ x7) << 4)); \
      } } }
#define MFMAQ(q)                                                                  \
  { __builtin_amdgcn_s_setprio(1);                                                \
    _Pragma("unroll") for (int mm = 0; mm < 2; ++mm)                              \
      _Pragma("unroll") for (int n = 0; n < 4; ++n) {                             \
        acc[(q) * 2 + mm][n] = MFMA16(af[mm][0], bfr[n][0], acc[(q) * 2 + mm][n]); \
        acc[(q) * 2 + mm][n] = MFMA16(af[mm][1], bfr[n][1], acc[(q) * 2 + mm][n]); \
      }                                                                           \
    __builtin_amdgcn_s_setprio(0); }
#define BARR __builtin_amdgcn_s_barrier()
#define LGK0 { asm volatile("s_waitcnt lgkmcnt(0)" ::: "memory"); __builtin_amdgcn_sched_barrier(0); }

  STG(0, 0, 0, 0); STG(0, 0, 1, 0); STG(0, 1, 0, 0); STG(0, 1, 1, 0);
  STG(1, 1, 0, 1); STG(1, 1, 1, 1); STG(1, 0, 0, 1);
  asm volatile("s_waitcnt vmcnt(6)" ::: "memory");
  __builtin_amdgcn_sched_barrier(0);
  BARR;

  const int NIT = HIDN / 128;
#pragma unroll 1
  for (int i = 0; i < NIT; ++i) {
    const int t2 = 2 * i + 2, t3 = 2 * i + 3;
    const bool nl_ = (i < NIT - 1);
    DSRA(0, 0); DSRB(0);
    STG(1, 0, 1, 2 * i + 1);
    asm volatile("s_waitcnt lgkmcnt(8)" ::: "memory");
    BARR; LGK0; MFMAQ(0); BARR;
    DSRA(0, 1);
    if (nl_) STG(0, 1, 0, t2);
    BARR; LGK0; MFMAQ(1); BARR;
    DSRA(0, 2);
    if (nl_) STG(0, 1, 1, t2);
    BARR; LGK0; MFMAQ(2); BARR;
    DSRA(0, 3);
    BARR; LGK0; MFMAQ(3);
    if (nl_) { asm volatile("s_waitcnt vmcnt(4)" ::: "memory"); }
    else     { asm volatile("s_waitcnt vmcnt(0)" ::: "memory"); }
    __builtin_amdgcn_sched_barrier(0);
    BARR;
    DSRA(1, 0); DSRB(1);
    if (nl_) STG(0, 0, 0, t2);
    asm volatile("s_waitcnt lgkmcnt(8)" ::: "memory");
    BARR; LGK0; MFMAQ(0); BARR;
    DSRA(1, 1);
    if (nl_) { STG(0, 0, 1, t2); STG(1, 1, 0, t3); }
    BARR; LGK0; MFMAQ(1); BARR;
    DSRA(1, 2);
    if (nl_) STG(1, 1, 1, t3);
    BARR; LGK0; MFMAQ(2); BARR;
    DSRA(1, 3);
    if (nl_) STG(1, 0, 0, t3);
    BARR; LGK0; MFMAQ(3);
    if (nl_) { asm volatile("s_waitcnt vmcnt(6)" ::: "memory"); __builtin_amdgcn_sched_barrier(0); }
    BARR;
  }
#undef STG
#undef DSRA
#undef DSRB
#undef MFMAQ

  const int gc0 = (int)bn + wc * 64;
  if (MODE == 1) {
    unsigned short* bout = (unsigned short*)p0;
#pragma unroll
    for (int m = 0; m < 8; ++m) {
      long r0 = bm + wr * 128 + m * 16 + lkg * 4;
#pragma unroll
      for (int n = 0; n < 4; n += 2) {
        int ggrp = (gc0 + n * 16) >> 5;
        long c = (long)ggrp * 16 + lr;
#pragma unroll
        for (int r = 0; r < 4; ++r) {
          float x = acc[m][n][r], g = acc[m][n + 1][r];
          float sv = x / (1.0f + __expf(-x)) * g;
          bout[(r0 + r) * 2048 + c] = f2bf(sv);
        }
      }
    }
  } else {  // MODE 0
    int bufid = gc0 >> 11;
    if (bufid == 2) {
      unsigned short* vT = (unsigned short*)p2;
#pragma unroll
      for (int m = 0; m < 8; ++m) {
        long r0 = bm + wr * 128 + m * 16 + lkg * 4;
        long bq = r0 >> 11;
        int s = (int)(r0 & 2047);
#pragma unroll
        for (int n = 0; n < 4; ++n) {
          int wcol = (gc0 + n * 16 + lr) & 2047;
          int hh = wcol >> 7, dd = wcol & 127;
          ushort4 pw;
          pw.x = f2bf(acc[m][n][0]); pw.y = f2bf(acc[m][n][1]);
          pw.z = f2bf(acc[m][n][2]); pw.w = f2bf(acc[m][n][3]);
          *(ushort4*)(vT + ((bq * 16 + hh) * 128 + dd) * (long)SEQ + s) = pw;
        }
      }
    } else {
      unsigned short* dst = (bufid == 0) ? (unsigned short*)p0 : (unsigned short*)p1;
      // q gets 1/sqrt(HD) * log2(e) folded in (flash softmax runs in log2 domain)
      const float qscale = (bufid == 0) ? 0.12751689f : 1.0f;
#pragma unroll
      for (int m = 0; m < 8; ++m) {
        long r0 = bm + wr * 128 + m * 16 + lkg * 4;
#pragma unroll
        for (int n = 0; n < 4; ++n) {
          int wcol = (gc0 + n * 16 + lr) & 2047;
          int f = wcol & 127, hh = wcol >> 7;
          int j = f >> 1, odd = f & 1;
          int oc = hh * 128 + (odd ? 64 : 0) + j;
#pragma unroll
          for (int r = 0; r < 4; ++r) {
            long row = r0 + r;
            int s = (int)(row & (SEQ - 1));
            float cv = cosT[s * 64 + j], sn = sinT[s * 64 + j];
            float v = acc[m][n][r];
            float o = __shfl_xor(v, 1);
            float res = (odd ? (v * cv + o * sn) : (v * cv - o * sn)) * qscale;
            dst[row * 2048 + oc] = f2bf(res);
          }
        }
      }
    }
  }
#undef BARR
#undef LGK0
}

// ---------------------------------------------------------------- GEMM 128x256, 4-phase, full reg-buffer
// BM=128 BN=256 BK=64, 512 thr / 8 waves (2Mx4N, per-wave 64x64). LDS 96 KB.
// A+B both register-buffered at each tile's first phase -> whole buffer free
// for restage one phase later; each tile staged as one 6-load unit with 2
// phases of slack before its vmcnt(6) gate. Never vmcnt(0) in-loop.
// MODE 2: f32 p0 = p1 + acc.  MODE 3: f32 p0 += acc.
template <int MODE>
__global__ __launch_bounds__(512, 2) void gemmWide_kernel(
    const unsigned short* __restrict__ A, const unsigned short* __restrict__ Bt,
    void* __restrict__ p0, const void* __restrict__ p1) {
  __shared__ unsigned short L[49152];   // [buf2][A:8192 | B:16384] shorts
  const int tid = threadIdx.x;
  const int wave = tid >> 6, lane = tid & 63;
  const int lr = lane & 15, lkg = lane >> 4;
  const int wr = wave >> 2, wc = wave & 3;
  const int x7 = lr & 7;
  // XCD swizzle: XCD x owns bx=x (1 MB B panel L2-resident), all 32 by.
  const int bid = (int)blockIdx.x;
  const int wg = (bid & 7) * 32 + (bid >> 3);
  const int bx = wg >> 5, by = wg & 31;
  const long bm = (long)by * 128, bn = (long)bx * 256;
  const int sslot = (lane & 7) ^ (lane >> 3);
  const unsigned short* Ag = A + (bm + wave * 8 + (lane >> 3)) * HIDN + sslot * 8;
  const unsigned short* Bg = Bt + (bn + wave * 8 + (lane >> 3)) * HIDN + sslot * 8;
  const char* Lc = (const char*)L;
  f32x4 acc[4][4] = {};
  bf16x8 af[4][2], bfr[4][2];

  // stage full tile -> buf b: A (2 gloads) + B (4 gloads)
#define STGALL(b, tile)                                                           \
  { const unsigned short* ga = Ag + (long)(tile) * 64;                            \
    unsigned short* da = &L[(b) * 24576 + wave * 8 * 64];                         \
    gload16(ga, da);                                                              \
    gload16(ga + (long)64 * HIDN, da + 4096);                                     \
    const unsigned short* gb = Bg + (long)(tile) * 64;                            \
    unsigned short* db = &L[(b) * 24576 + 8192 + wave * 8 * 64];                  \
    gload16(gb, db);                                                              \
    gload16(gb + (long)64 * HIDN, db + 4096);                                     \
    gload16(gb + (long)128 * HIDN, db + 8192);                                    \
    gload16(gb + (long)192 * HIDN, db + 12288); }
  // read ALL fragments of buf b into registers (16 x ds_read_b128)
#define DSRALL(b)                                                                 \
  { _Pragma("unroll") for (int n = 0; n < 4; ++n) {                               \
      int row = wc * 64 + n * 16 + lr;                                            \
      _Pragma("unroll") for (int ks = 0; ks < 2; ++ks) {                          \
        int s = ks * 4 + lkg;                                                     \
        bfr[n][ks] = *(const bf16x8*)(Lc + (b) * 49152 + 16384 + row * 128 + ((s ^ x7) << 4)); \
      } }                                                                         \
    _Pragma("unroll") for (int mm = 0; mm < 4; ++mm) {                            \
      int row = wr * 64 + mm * 16 + lr;                                           \
      _Pragma("unroll") for (int ks = 0; ks < 2; ++ks) {                          \
        int s = ks * 4 + lkg;                                                     \
        af[mm][ks] = *(const bf16x8*)(Lc + (b) * 49152 + row * 128 + ((s ^ x7) << 4)); \
      } } }
#define MFMAH(h)                                                                  \
  { __builtin_amdgcn_s_setprio(1);                                                \
    _Pragma("unroll") for (int mm = 2 * (h); mm < 2 * (h) + 2; ++mm)              \
      _Pragma("unroll") for (int n = 0; n < 4; ++n) {                             \
        acc[mm][n] = MFMA16(af[mm][0], bfr[n][0], acc[mm][n]);                    \
        acc[mm][n] = MFMA16(af[mm][1], bfr[n][1], acc[mm][n]);                    \
      }                                                                           \
    __builtin_amdgcn_s_setprio(0); }
#define BARR __builtin_amdgcn_s_barrier()
#define LGK0 { asm volatile("s_waitcnt lgkmcnt(0)" ::: "memory"); __builtin_amdgcn_sched_barrier(0); }

  // prologue: t0 -> buf0, t1 -> buf1 (6+6 loads); drain t0, keep t1 flying
  STGALL(0, 0);
  STGALL(1, 1);
  asm volatile("s_waitcnt vmcnt(6)" ::: "memory");
  __builtin_amdgcn_sched_barrier(0);
  BARR;

  const int NIT = HIDN / 128;   // 16 iterations, 2 K-tiles each
#pragma unroll 1
  for (int i = 0; i < NIT; ++i) {
    const int t2 = 2 * i + 2, t3 = 2 * i + 3;
    const bool nl_ = (i < NIT - 1);
    // P1: buf0 -> regs (16 reads)
    DSRALL(0);
    asm volatile("s_waitcnt lgkmcnt(8)" ::: "memory");
    BARR; LGK0; MFMAH(0); BARR;
    // P2: restage buf0 with t2 (all waves' buf0 reads completed at end-P1 barrier)
    if (nl_) STGALL(0, t2);
    MFMAH(1);
    if (nl_) { asm volatile("s_waitcnt vmcnt(6)" ::: "memory"); }   // drain t1, t2 flying
    else     { asm volatile("s_waitcnt vmcnt(0)" ::: "memory"); }   // tail: drain t1
    __builtin_amdgcn_sched_barrier(0);
    BARR;
    // P3: buf1 -> regs
    DSRALL(1);
    asm volatile("s_waitcnt lgkmcnt(8)" ::: "memory");
    BARR; LGK0; MFMAH(0); BARR;
    // P4: restage buf1 with t3
    if (nl_) {
      STGALL(1, t3);
      MFMAH(1);
      asm volatile("s_waitcnt vmcnt(6)" ::: "memory");              // drain t2, t3 flying
      __builtin_amdgcn_sched_barrier(0);
    } else {
      MFMAH(1);
    }
    BARR;
  }
#undef STGALL
#undef DSRALL
#undef MFMAH
#undef BARR
#undef LGK0

  float* fout = (float*)p0;
  const float* addsrc = (const float*)p1;
#pragma unroll
  for (int m = 0; m < 4; ++m) {
    long r0 = bm + wr * 64 + m * 16 + lkg * 4;
#pragma unroll
    for (int n = 0; n < 4; ++n) {
      long c = bn + wc * 64 + n * 16 + lr;
#pragma unroll
      for (int r = 0; r < 4; ++r) {
        long idx = (r0 + r) * 2048 + c;
        if (MODE == 2) fout[idx] = addsrc[idx] + acc[m][n][r];
        else fout[idx] = fout[idx] + acc[m][n][r];
      }
    }
  }
}

// ---------------------------------------------------------------- flash attention (r8 known-good)
__global__ __launch_bounds__(256, 3) void flash_attn_kernel(
    const unsigned short* __restrict__ Q, const unsigned short* __restrict__ Kb,
    const unsigned short* __restrict__ vT, unsigned short* __restrict__ O) {
  __shared__ unsigned short Ks[64 * 128];
  __shared__ unsigned short Vs[128 * 64];
  __shared__ unsigned short Ps[4][16][72];
  const int bid = (int)blockIdx.x;
  const int wg = (bid & 7) * 128 + (bid >> 3);
  const int qt = wg & 31, h = (wg >> 5) & 15, b = wg >> 9;
  const int tid = threadIdx.x, wave = tid >> 6, lane = tid & 63;
  const int lr = lane & 15, lkg = lane >> 4, lk = lkg * 8;
  const long rowbase = (long)b * SEQ;
  const int qrow0 = qt * 64 + wave * 16;
  bf16x8 aq[4];
#pragma unroll
  for (int ks = 0; ks < 4; ++ks)
    aq[ks] = *(const bf16x8*)(Q + (rowbase + qrow0 + lr) * HIDN + h * HD + ks * 32 + lk);
  const unsigned short* vbase = vT + ((long)(b * 16 + h) * 128) * SEQ;  // [d][s]
  const int kr_ = tid >> 4, kc_ = tid & 15;
  const int vd_ = tid >> 3, vc_ = tid & 7;
  int4 kreg[4], vreg[4];
  f32x4 acc[8] = {};
  float m_ = -3.0e38f, l_ = 0.f;

#define GLOADKV(kv0_)                                                              \
  { _Pragma("unroll")                                                              \
    for (int j = 0; j < 4; ++j)                                                    \
      kreg[j] = *(const int4*)(Kb + (rowbase + (kv0_) + kr_ + j * 16) * HIDN + h * HD + kc_ * 8); \
    _Pragma("unroll")                                                              \
    for (int j = 0; j < 4; ++j)                                                    \
      vreg[j] = *(const int4*)(vbase + (long)(vd_ + j * 32) * SEQ + (kv0_) + vc_ * 8); }
#define DSWRITEKV()                                                                \
  { _Pragma("unroll")                                                              \
    for (int j = 0; j < 4; ++j) {                                                  \
      int row = kr_ + j * 16;                                                      \
      *(int4*)((char*)Ks + row * 256 + ((kc_ ^ (row & 15)) << 4)) = kreg[j];       \
    }                                                                              \
    _Pragma("unroll")                                                              \
    for (int j = 0; j < 4; ++j) {                                                  \
      int d = vd_ + j * 32;                                                        \
      *(int4*)((char*)Vs + d * 128 + ((vc_ ^ (d & 7)) << 4)) = vreg[j];            \
    } }

  GLOADKV(0);
  asm volatile("s_waitcnt vmcnt(0)" ::: "memory");
  DSWRITEKV();
  asm volatile("s_waitcnt lgkmcnt(0)" ::: "memory");
  __builtin_amdgcn_sched_barrier(0);
  asm volatile("s_barrier" ::: "memory");

  for (int t = 0; t < SEQ / 64; ++t) {
    if (t + 1 < SEQ / 64) GLOADKV((long)(t + 1) * 64);
    const char* ksb = (const char*)Ks;
    f32x4 sa[4] = {};
#pragma unroll
    for (int n = 0; n < 4; ++n) {
      int row = n * 16 + lr;
#pragma unroll
      for (int ks = 0; ks < 4; ++ks) {
        bf16x8 bk = *(const bf16x8*)(ksb + row * 256 + (((ks * 4 + lkg) ^ (row & 15)) << 4));
        sa[n] = MFMA16(bk, aq[ks], sa[n]);
      }
    }
    float pmax = sa[0][0];
#pragma unroll
    for (int n = 0; n < 4; ++n)
#pragma unroll
      for (int r = 0; r < 4; ++r) pmax = fmaxf(pmax, sa[n][r]);
    pmax = fmaxf(pmax, __shfl_xor(pmax, 16));
    pmax = fmaxf(pmax, __shfl_xor(pmax, 32));
    if (__all(pmax - m_ <= 11.54f)) {
      float psum = 0.f;
#pragma unroll
      for (int n = 0; n < 4; ++n)
#pragma unroll
        for (int r = 0; r < 4; ++r) {
          float p = exp2f(sa[n][r] - m_);
          sa[n][r] = p;
          psum += p;
        }
      psum += __shfl_xor(psum, 16);
      psum += __shfl_xor(psum, 32);
      l_ += psum;
    } else {
      float mnew = fmaxf(m_, pmax);
      float corr = exp2f(m_ - mnew);
      float psum = 0.f;
#pragma unroll
      for (int n = 0; n < 4; ++n)
#pragma unroll
        for (int r = 0; r < 4; ++r) {
          float p = exp2f(sa[n][r] - mnew);
          sa[n][r] = p;
          psum += p;
        }
      psum += __shfl_xor(psum, 16);
      psum += __shfl_xor(psum, 32);
      l_ = l_ * corr + psum;
      m_ = mnew;
      float corr4[4];
#pragma unroll
      for (int r = 0; r < 4; ++r) corr4[r] = __shfl(corr, 4 * lkg + r);
#pragma unroll
      for (int df = 0; df < 8; ++df)
#pragma unroll
        for (int r = 0; r < 4; ++r) acc[df][r] *= corr4[r];
    }
#pragma unroll
    for (int n = 0; n < 4; ++n) {
      ushort4 pw;
      pw.x = f2bf(sa[n][0]); pw.y = f2bf(sa[n][1]);
      pw.z = f2bf(sa[n][2]); pw.w = f2bf(sa[n][3]);
      *(ushort4*)&Ps[wave][lr][n * 16 + 4 * lkg] = pw;
    }
    bf16x8 pa0 = *(const bf16x8*)&Ps[wave][lr][lk];
    bf16x8 pa1 = *(const bf16x8*)&Ps[wave][lr][32 + lk];
    const char* vsb = (const char*)Vs;
#pragma unroll
    for (int df = 0; df < 8; ++df) {
      int row = df * 16 + lr;
      int x7 = row & 7;
      bf16x8 bv0 = *(const bf16x8*)(vsb + row * 128 + ((lkg ^ x7) << 4));
      bf16x8 bv1 = *(const bf16x8*)(vsb + row * 128 + (((4 + lkg) ^ x7) << 4));
      acc[df] = MFMA16(pa0, bv0, acc[df]);
      acc[df] = MFMA16(pa1, bv1, acc[df]);
    }
    asm volatile("s_barrier" ::: "memory");
    if (t + 1 < SEQ / 64) {
      asm volatile("s_waitcnt vmcnt(0)" ::: "memory");
      DSWRITEKV();
      asm volatile("s_waitcnt lgkmcnt(0)" ::: "memory");
      __builtin_amdgcn_sched_barrier(0);
      asm volatile("s_barrier" ::: "memory");
    }
  }
#undef GLOADKV
#undef DSWRITEKV
  float invl = 1.0f / l_;
  float invl4[4];
#pragma unroll
  for (int r = 0; r < 4; ++r) invl4[r] = __shfl(invl, 4 * lkg + r);
#pragma unroll
  for (int r = 0; r < 4; ++r) {
    long orow = rowbase + qrow0 + lkg * 4 + r;
#pragma unroll
    for (int df = 0; df < 8; ++df)
      O[orow * HIDN + h * HD + df * 16 + lr] = f2bf(acc[df][r] * invl4[r]);
  }
}

// ---------------------------------------------------------------- launcher
extern "C" void kernel_launch(void* const* d_in, const int* in_sizes, int n_in,
                              void* d_out, int out_size, void* d_ws, size_t ws_size,
                              hipStream_t stream) {
  const float* hidden = (const float*)d_in[0];
  const float* Wq = (const float*)d_in[1];
  const float* Wk = (const float*)d_in[2];
  const float* Wv = (const float*)d_in[3];
  const float* Wo = (const float*)d_in[4];
  const float* w1 = (const float*)d_in[5];
  const float* w2 = (const float*)d_in[6];
  const float* w3 = (const float*)d_in[7];
  const float* ln1 = (const float*)d_in[8];
  const float* ln2 = (const float*)d_in[9];
  float* out = (float*)d_out;

  char* ws = (char*)d_ws;
  size_t off = 0;
  auto alloc = [&](size_t bytes) -> void* {
    void* p = ws + off;
    off += (bytes + 255) & ~(size_t)255;
    return p;
  };
  unsigned short* wblk = (unsigned short*)alloc((size_t)(2048L * 6 + 2048) * HIDN * 2);
  unsigned short* wQ = wblk;
  unsigned short* wG = wblk + (size_t)8192 * HIDN;
  unsigned short* wO = wblk + (size_t)6144 * HIDN;
  unsigned short* wD = wblk + (size_t)12288 * HIDN;
  unsigned short* xb   = (unsigned short*)alloc((size_t)NROWS * HIDN * 2);
  unsigned short* qb   = (unsigned short*)alloc((size_t)NROWS * HIDN * 2);
  unsigned short* kb   = (unsigned short*)alloc((size_t)NROWS * HIDN * 2);
  unsigned short* vTb  = (unsigned short*)alloc((size_t)NROWS * HIDN * 2);
  unsigned short* ctxb = (unsigned short*)alloc((size_t)NROWS * HIDN * 2);
  float* cosT = (float*)alloc((size_t)SEQ * 64 * 4);
  float* sinT = (float*)alloc((size_t)SEQ * 64 * 4);
  if (off > ws_size) return;

  transpose_all_kernel<<<dim3(HIDN / 64, HIDN / 64, 7), 256, 0, stream>>>(
      Wq, Wk, Wv, Wo, w1, w3, w2, wblk);
  rope_table_kernel<<<SEQ, 64, 0, stream>>>(cosT, sinT);

  rmsnorm_kernel<<<NROWS, 256, 0, stream>>>(hidden, ln1, xb);

  // QKV (N=6144) 8-phase 256^2 with rope epilogue -> qb, kb, vTb
  gemm256_kernel<0><<<(6144 / 256) * (NROWS / 256), 512, 0, stream>>>(
      xb, wQ, 6144 / 256, qb, kb, vTb, cosT, sinT);

  flash_attn_kernel<<<(SEQ / 64) * NHEAD * BATCH, 256, 0, stream>>>(qb, kb, vTb, ctxb);

  // attn_out + residual -> out (f32), 128x256 4-phase (256 blocks, 1 round)
  gemmWide_kernel<2><<<256, 512, 0, stream>>>(ctxb, wO, out, hidden);

  rmsnorm_kernel<<<NROWS, 256, 0, stream>>>(out, ln2, xb);

  // gate: silu(y@w1)*(y@w3) (N=4096 interleaved) -> qb
  gemm256_kernel<1><<<(4096 / 256) * (NROWS / 256), 512, 0, stream>>>(
      xb, wG, 4096 / 256, qb, nullptr, nullptr, nullptr, nullptr);

  // down: out += gs @ w2, 128x256 4-phase (256 blocks, 1 round)
  gemmWide_kernel<3><<<256, 512, 0, stream>>>(qb, wD, out, nullptr);
}

// Round 17
// 444.980 us; speedup vs baseline: 1.0412x; 1.0412x over previous
//
#include <hip/hip_runtime.h>

#define HIDN 2048
#define NHEAD 16
#define HD 128
#define SEQ 2048
#define BATCH 2
#define NROWS (BATCH*SEQ)   // 4096

typedef __bf16 bf16_t;
typedef bf16_t bf16x8 __attribute__((ext_vector_type(8)));
typedef float f32x4 __attribute__((ext_vector_type(4)));
typedef unsigned short ushort8 __attribute__((ext_vector_type(8)));

#define AS1 __attribute__((address_space(1)))
#define AS3 __attribute__((address_space(3)))

__device__ __forceinline__ unsigned short f2bf(float x) {
  union { bf16_t b; unsigned short u; } cv; cv.b = (bf16_t)x; return cv.u;
}

#define MFMA16(a,b,c) __builtin_amdgcn_mfma_f32_16x16x32_bf16((a),(b),(c),0,0,0)

__device__ __forceinline__ void gload16(const void* g, void* l) {
  __builtin_amdgcn_global_load_lds((const AS1 void*)g, (AS3 void*)l, 16, 0, 0);
}

// ---------------------------------------------------------------- fused weight transpose+cvt
__global__ __launch_bounds__(256) void transpose_all_kernel(
    const float* __restrict__ Wq, const float* __restrict__ Wk,
    const float* __restrict__ Wv, const float* __restrict__ Wo,
    const float* __restrict__ w1, const float* __restrict__ w3,
    const float* __restrict__ w2, unsigned short* __restrict__ wblk) {
  const int z = blockIdx.z;
  const float* W; unsigned short* dstb; int tmode = 0, half = 0;
  switch (z) {
    case 0: W = Wq; dstb = wblk;                       tmode = 1; break;
    case 1: W = Wk; dstb = wblk + (size_t)2048 * HIDN; tmode = 1; break;
    case 2: W = Wv; dstb = wblk + (size_t)4096 * HIDN; break;
    case 3: W = Wo; dstb = wblk + (size_t)6144 * HIDN; break;
    case 4: W = w1; dstb = wblk + (size_t)8192 * HIDN; tmode = 2; half = 0; break;
    case 5: W = w3; dstb = wblk + (size_t)8192 * HIDN; tmode = 2; half = 1; break;
    default: W = w2; dstb = wblk + (size_t)12288 * HIDN; break;
  }
  __shared__ float t[64][69];
  const int tid = threadIdx.x;
  const int bn = blockIdx.x * 64, bk = blockIdx.y * 64;
  const int lc = (tid & 15) * 4, lrw = tid >> 4;
#pragma unroll
  for (int i = 0; i < 4; ++i) {
    int k = bk + lrw + i * 16;
    float4 v = *(const float4*)(W + (long)k * HIDN + bn + lc);
    t[lrw + i * 16][lc] = v.x; t[lrw + i * 16][lc + 1] = v.y;
    t[lrw + i * 16][lc + 2] = v.z; t[lrw + i * 16][lc + 3] = v.w;
  }
  __syncthreads();
  const int nl = tid >> 2, k0 = (tid & 3) * 16;
  int n = bn + nl;
  int dst;
  if (tmode == 0) dst = n;
  else if (tmode == 1) { int d = n & 127; dst = (n & ~127) | ((d & 63) << 1) | (d >> 6); }
  else dst = (n >> 4) * 32 + half * 16 + (n & 15);
  unsigned short* orow = dstb + (long)dst * HIDN + bk + k0;
#pragma unroll
  for (int j = 0; j < 16; j += 8) {
    ushort8 o;
#pragma unroll
    for (int jj = 0; jj < 8; ++jj) o[jj] = f2bf(t[k0 + j + jj][nl]);
    *(ushort8*)(orow + j) = o;
  }
}

// ---------------------------------------------------------------- rope tables
__global__ void rope_table_kernel(float* __restrict__ cosT, float* __restrict__ sinT) {
  int s = blockIdx.x, d = threadIdx.x;
  float invf = powf(10000.0f, (-2.0f * (float)d) / 128.0f);
  float ang = (float)s * invf;
  cosT[s * 64 + d] = cosf(ang);
  sinT[s * 64 + d] = sinf(ang);
}

// ---------------------------------------------------------------- rmsnorm
__global__ __launch_bounds__(256) void rmsnorm_kernel(
    const float* __restrict__ x, const float* __restrict__ w, unsigned short* __restrict__ out) {
  long row = blockIdx.x;
  const float* xr = x + row * HIDN;
  int c0 = threadIdx.x * 4;
  float4 v0 = *(const float4*)(xr + c0);
  float4 v1 = *(const float4*)(xr + 1024 + c0);
  float s = v0.x*v0.x + v0.y*v0.y + v0.z*v0.z + v0.w*v0.w
          + v1.x*v1.x + v1.y*v1.y + v1.z*v1.z + v1.w*v1.w;
#pragma unroll
  for (int off = 1; off < 64; off <<= 1) s += __shfl_xor(s, off);
  __shared__ float red[4];
  if ((threadIdx.x & 63) == 0) red[threadIdx.x >> 6] = s;
  __syncthreads();
  float tot = red[0] + red[1] + red[2] + red[3];
  float r = 1.0f / sqrtf(tot * (1.0f / (float)HIDN) + 1e-6f);
  float4 w0 = *(const float4*)(w + c0);
  float4 w1 = *(const float4*)(w + 1024 + c0);
  ushort4 o0, o1;
  o0.x = f2bf(v0.x * r * w0.x); o0.y = f2bf(v0.y * r * w0.y);
  o0.z = f2bf(v0.z * r * w0.z); o0.w = f2bf(v0.w * r * w0.w);
  o1.x = f2bf(v1.x * r * w1.x); o1.y = f2bf(v1.y * r * w1.y);
  o1.z = f2bf(v1.z * r * w1.z); o1.w = f2bf(v1.w * r * w1.w);
  *(ushort4*)(out + row * HIDN + c0) = o0;
  *(ushort4*)(out + row * HIDN + 1024 + c0) = o1;
}

// ---------------------------------------------------------------- GEMM 256x256, 8-phase schedule
// MODE 0: QKV+rope (q pre-scaled by 1/sqrt(HD)*log2e); v transposed to p2.
// MODE 1: gate silu-mul.
template <int MODE>
__global__ __launch_bounds__(512, 2) void gemm256_kernel(
    const unsigned short* __restrict__ A, const unsigned short* __restrict__ Bt,
    int nbx,
    void* __restrict__ p0, void* __restrict__ p1, void* __restrict__ p2,
    const float* __restrict__ cosT, const float* __restrict__ sinT) {
  __shared__ unsigned short L[65536];   // [buf2][mat2][half2][128*64]
  const int tid = threadIdx.x;
  const int wave = tid >> 6, lane = tid & 63;
  const int lr = lane & 15, lkg = lane >> 4;
  const int wr = wave >> 2, wc = wave & 3;
  const int x7 = lr & 7;
  const int nwg = (int)gridDim.x;
  const int bid = (int)blockIdx.x;
  const int wg = (bid & 7) * (nwg >> 3) + (bid >> 3);
  const int bx = wg % nbx, by = wg / nbx;
  const long bm = (long)by * 256, bn = (long)bx * 256;
  const int sslot = (lane & 7) ^ (lane >> 3);
  const unsigned short* Ag = A + (bm + wave * 8 + (lane >> 3)) * HIDN + sslot * 8;
  const unsigned short* Bg = Bt + (bn + wave * 8 + (lane >> 3)) * HIDN + sslot * 8;
  const char* Lc = (const char*)L;
  f32x4 acc[8][4] = {};
  bf16x8 af[2][2], bfr[4][2];

#define STG(b, mat, half, tile)                                                   \
  {                                                                               \
    const unsigned short* gsrc = ((mat) ? Bg : Ag) + ((long)(half) * 128) * HIDN + (long)(tile) * 64; \
    unsigned short* ldst = &L[((4 * (b) + 2 * (mat) + (half)) * 8192) + wave * 8 * 64]; \
    gload16(gsrc, ldst);                                                          \
    gload16(gsrc + (long)64 * HIDN, ldst + 4096);                                 \
  }
#define DSRA(b, q)                                                                \
  { _Pragma("unroll") for (int mm = 0; mm < 2; ++mm) {                            \
      int row128 = ((q) * 2 + mm) * 16 + lr;                                      \
      _Pragma("unroll") for (int ks = 0; ks < 2; ++ks) {                          \
        int s = ks * 4 + lkg;                                                     \
        af[mm][ks] = *(const bf16x8*)(Lc + (4 * (b) + wr) * 16384 + row128 * 128 + ((s ^ x7) << 4)); \
      } } }
#define DSRB(b)                                                                   \
  { _Pragma("unroll") for (int n = 0; n < 4; ++n) {                               \
      int row128 = (wc & 1) * 64 + n * 16 + lr;                                   \
      _Pragma("unroll") for (int ks = 0; ks < 2; ++ks) {                          \
        int s = ks * 4 + lkg;                                                     \
        bfr[n][ks] = *(const bf16x8*)(Lc + (4 * (b) + 2 + (wc >> 1)) * 16384 + row128 * 128 + ((s ^ x7) << 4)); \
      } } }
#define MFMAQ(q)                                                                  \
  { __builtin_amdgcn_s_setprio(1);                                                \
    _Pragma("unroll") for (int mm = 0; mm < 2; ++mm)                              \
      _Pragma("unroll") for (int n = 0; n < 4; ++n) {                             \
        acc[(q) * 2 + mm][n] = MFMA16(af[mm][0], bfr[n][0], acc[(q) * 2 + mm][n]); \
        acc[(q) * 2 + mm][n] = MFMA16(af[mm][1], bfr[n][1], acc[(q) * 2 + mm][n]); \
      }                                                                           \
    __builtin_amdgcn_s_setprio(0); }
#define BARR __builtin_amdgcn_s_barrier()
#define LGK0 { asm volatile("s_waitcnt lgkmcnt(0)" ::: "memory"); __builtin_amdgcn_sched_barrier(0); }

  STG(0, 0, 0, 0); STG(0, 0, 1, 0); STG(0, 1, 0, 0); STG(0, 1, 1, 0);
  STG(1, 1, 0, 1); STG(1, 1, 1, 1); STG(1, 0, 0, 1);
  asm volatile("s_waitcnt vmcnt(6)" ::: "memory");
  __builtin_amdgcn_sched_barrier(0);
  BARR;

  const int NIT = HIDN / 128;
#pragma unroll 1
  for (int i = 0; i < NIT; ++i) {
    const int t2 = 2 * i + 2, t3 = 2 * i + 3;
    const bool nl_ = (i < NIT - 1);
    DSRA(0, 0); DSRB(0);
    STG(1, 0, 1, 2 * i + 1);
    asm volatile("s_waitcnt lgkmcnt(8)" ::: "memory");
    BARR; LGK0; MFMAQ(0); BARR;
    DSRA(0, 1);
    if (nl_) STG(0, 1, 0, t2);
    BARR; LGK0; MFMAQ(1); BARR;
    DSRA(0, 2);
    if (nl_) STG(0, 1, 1, t2);
    BARR; LGK0; MFMAQ(2); BARR;
    DSRA(0, 3);
    BARR; LGK0; MFMAQ(3);
    if (nl_) { asm volatile("s_waitcnt vmcnt(4)" ::: "memory"); }
    else     { asm volatile("s_waitcnt vmcnt(0)" ::: "memory"); }
    __builtin_amdgcn_sched_barrier(0);
    BARR;
    DSRA(1, 0); DSRB(1);
    if (nl_) STG(0, 0, 0, t2);
    asm volatile("s_waitcnt lgkmcnt(8)" ::: "memory");
    BARR; LGK0; MFMAQ(0); BARR;
    DSRA(1, 1);
    if (nl_) { STG(0, 0, 1, t2); STG(1, 1, 0, t3); }
    BARR; LGK0; MFMAQ(1); BARR;
    DSRA(1, 2);
    if (nl_) STG(1, 1, 1, t3);
    BARR; LGK0; MFMAQ(2); BARR;
    DSRA(1, 3);
    if (nl_) STG(1, 0, 0, t3);
    BARR; LGK0; MFMAQ(3);
    if (nl_) { asm volatile("s_waitcnt vmcnt(6)" ::: "memory"); __builtin_amdgcn_sched_barrier(0); }
    BARR;
  }
#undef STG
#undef DSRA
#undef DSRB
#undef MFMAQ

  const int gc0 = (int)bn + wc * 64;
  if (MODE == 1) {
    unsigned short* bout = (unsigned short*)p0;
#pragma unroll
    for (int m = 0; m < 8; ++m) {
      long r0 = bm + wr * 128 + m * 16 + lkg * 4;
#pragma unroll
      for (int n = 0; n < 4; n += 2) {
        int ggrp = (gc0 + n * 16) >> 5;
        long c = (long)ggrp * 16 + lr;
#pragma unroll
        for (int r = 0; r < 4; ++r) {
          float x = acc[m][n][r], g = acc[m][n + 1][r];
          float sv = x / (1.0f + __expf(-x)) * g;
          bout[(r0 + r) * 2048 + c] = f2bf(sv);
        }
      }
    }
  } else {  // MODE 0
    int bufid = gc0 >> 11;
    if (bufid == 2) {
      unsigned short* vT = (unsigned short*)p2;
#pragma unroll
      for (int m = 0; m < 8; ++m) {
        long r0 = bm + wr * 128 + m * 16 + lkg * 4;
        long bq = r0 >> 11;
        int s = (int)(r0 & 2047);
#pragma unroll
        for (int n = 0; n < 4; ++n) {
          int wcol = (gc0 + n * 16 + lr) & 2047;
          int hh = wcol >> 7, dd = wcol & 127;
          ushort4 pw;
          pw.x = f2bf(acc[m][n][0]); pw.y = f2bf(acc[m][n][1]);
          pw.z = f2bf(acc[m][n][2]); pw.w = f2bf(acc[m][n][3]);
          *(ushort4*)(vT + ((bq * 16 + hh) * 128 + dd) * (long)SEQ + s) = pw;
        }
      }
    } else {
      unsigned short* dst = (bufid == 0) ? (unsigned short*)p0 : (unsigned short*)p1;
      // q gets 1/sqrt(HD) * log2(e) folded in (flash softmax runs in log2 domain)
      const float qscale = (bufid == 0) ? 0.12751689f : 1.0f;
#pragma unroll
      for (int m = 0; m < 8; ++m) {
        long r0 = bm + wr * 128 + m * 16 + lkg * 4;
#pragma unroll
        for (int n = 0; n < 4; ++n) {
          int wcol = (gc0 + n * 16 + lr) & 2047;
          int f = wcol & 127, hh = wcol >> 7;
          int j = f >> 1, odd = f & 1;
          int oc = hh * 128 + (odd ? 64 : 0) + j;
#pragma unroll
          for (int r = 0; r < 4; ++r) {
            long row = r0 + r;
            int s = (int)(row & (SEQ - 1));
            float cv = cosT[s * 64 + j], sn = sinT[s * 64 + j];
            float v = acc[m][n][r];
            float o = __shfl_xor(v, 1);
            float res = (odd ? (v * cv + o * sn) : (v * cv - o * sn)) * qscale;
            dst[row * 2048 + oc] = f2bf(res);
          }
        }
      }
    }
  }
#undef BARR
#undef LGK0
}

// ---------------------------------------------------------------- GEMM 128x256, 4-phase (r15 best)
// BM=128 BN=256 BK=64, 512 thr / 8 waves (2Mx4N, per-wave 64x64). LDS 96 KB;
// grid 256 = exactly 1 round. Ledger: P1{readB+A01 buf0, stage A(t1)->b1},
// P2{readA23 buf0, stage B(t2)->b0 x2, vmcnt(4)}, P3{readB+A01 buf1, stage
// A(t2)->b0}, P4{readA23 buf1, stage B(t3)->b1 x2, vmcnt(4)}.
// MODE 2: f32 p0 = p1 + acc.  MODE 3: f32 p0 += acc.
template <int MODE>
__global__ __launch_bounds__(512, 2) void gemmWide_kernel(
    const unsigned short* __restrict__ A, const unsigned short* __restrict__ Bt,
    void* __restrict__ p0, const void* __restrict__ p1) {
  __shared__ unsigned short L[49152];   // [buf2][A:8192 | B:16384] shorts
  const int tid = threadIdx.x;
  const int wave = tid >> 6, lane = tid & 63;
  const int lr = lane & 15, lkg = lane >> 4;
  const int wr = wave >> 2, wc = wave & 3;
  const int x7 = lr & 7;
  // XCD swizzle: XCD x owns bx=x (1 MB B panel L2-resident), all 32 by.
  const int bid = (int)blockIdx.x;
  const int wg = (bid & 7) * 32 + (bid >> 3);
  const int bx = wg >> 5, by = wg & 31;
  const long bm = (long)by * 128, bn = (long)bx * 256;
  const int sslot = (lane & 7) ^ (lane >> 3);
  const unsigned short* Ag = A + (bm + wave * 8 + (lane >> 3)) * HIDN + sslot * 8;
  const unsigned short* Bg = Bt + (bn + wave * 8 + (lane >> 3)) * HIDN + sslot * 8;
  const char* Lc = (const char*)L;
  f32x4 acc[4][4] = {};
  bf16x8 af[2][2], bfr[4][2];

#define STGA(b, tile)                                                             \
  { const unsigned short* g = Ag + (long)(tile) * 64;                             \
    unsigned short* d = &L[(b) * 24576 + wave * 8 * 64];                          \
    gload16(g, d); gload16(g + (long)64 * HIDN, d + 4096); }
#define STGB(b, hh, tile)                                                         \
  { const unsigned short* g = Bg + ((long)(hh) * 128) * HIDN + (long)(tile) * 64; \
    unsigned short* d = &L[(b) * 24576 + 8192 + (hh) * 8192 + wave * 8 * 64];     \
    gload16(g, d); gload16(g + (long)64 * HIDN, d + 4096); }
#define DSRA2(b, p)                                                               \
  { _Pragma("unroll") for (int mm = 0; mm < 2; ++mm) {                            \
      int row = wr * 64 + ((p) * 2 + mm) * 16 + lr;                               \
      _Pragma("unroll") for (int ks = 0; ks < 2; ++ks) {                          \
        int s = ks * 4 + lkg;                                                     \
        af[mm][ks] = *(const bf16x8*)(Lc + (b) * 49152 + row * 128 + ((s ^ x7) << 4)); \
      } } }
#define DSRBW(b)                                                                  \
  { _Pragma("unroll") for (int n = 0; n < 4; ++n) {                               \
      int row = wc * 64 + n * 16 + lr;                                            \
      _Pragma("unroll") for (int ks = 0; ks < 2; ++ks) {                          \
        int s = ks * 4 + lkg;                                                     \
        bfr[n][ks] = *(const bf16x8*)(Lc + (b) * 49152 + 16384 + row * 128 + ((s ^ x7) << 4)); \
      } } }
#define MFMAP(p)                                                                  \
  { __builtin_amdgcn_s_setprio(1);                                                \
    _Pragma("unroll") for (int mm = 0; mm < 2; ++mm)                              \
      _Pragma("unroll") for (int n = 0; n < 4; ++n) {                             \
        acc[(p) * 2 + mm][n] = MFMA16(af[mm][0], bfr[n][0], acc[(p) * 2 + mm][n]); \
        acc[(p) * 2 + mm][n] = MFMA16(af[mm][1], bfr[n][1], acc[(p) * 2 + mm][n]); \
      }                                                                           \
    __builtin_amdgcn_s_setprio(0); }
#define BARR __builtin_amdgcn_s_barrier()
#define LGK0 { asm volatile("s_waitcnt lgkmcnt(0)" ::: "memory"); __builtin_amdgcn_sched_barrier(0); }

  // prologue: t0 full -> buf0 (6 loads), B(t1) -> buf1 (4 loads)
  STGA(0, 0); STGB(0, 0, 0); STGB(0, 1, 0);
  STGB(1, 0, 1); STGB(1, 1, 1);
  asm volatile("s_waitcnt vmcnt(4)" ::: "memory");   // t0's 6 loads landed
  __builtin_amdgcn_sched_barrier(0);
  BARR;

  const int NIT = HIDN / 128;   // 16
#pragma unroll 1
  for (int i = 0; i < NIT; ++i) {
    const int t1 = 2 * i + 1, t2 = 2 * i + 2, t3 = 2 * i + 3;
    const bool nl_ = (i < NIT - 1);
    // P1: buf0 {B full + A m01}; stage A(t1)->buf1
    DSRBW(0); DSRA2(0, 0);
    STGA(1, t1);
    asm volatile("s_waitcnt lgkmcnt(8)" ::: "memory");
    BARR; LGK0; MFMAP(0); BARR;
    // P2: buf0 {A m23}; stage B(t2)->buf0; gate buf1(t1)
    DSRA2(0, 1);
    if (nl_) { STGB(0, 0, t2); STGB(0, 1, t2); }
    BARR; LGK0; MFMAP(1);
    if (nl_) { asm volatile("s_waitcnt vmcnt(4)" ::: "memory"); }
    else     { asm volatile("s_waitcnt vmcnt(0)" ::: "memory"); }
    __builtin_amdgcn_sched_barrier(0);
    BARR;
    // P3: buf1 {B full + A m01}; stage A(t2)->buf0
    DSRBW(1); DSRA2(1, 0);
    if (nl_) STGA(0, t2);
    asm volatile("s_waitcnt lgkmcnt(8)" ::: "memory");
    BARR; LGK0; MFMAP(0); BARR;
    // P4: buf1 {A m23}; stage B(t3)->buf1; gate buf0(t2)
    DSRA2(1, 1);
    if (nl_) { STGB(1, 0, t3); STGB(1, 1, t3); }
    BARR; LGK0; MFMAP(1);
    if (nl_) { asm volatile("s_waitcnt vmcnt(4)" ::: "memory"); __builtin_amdgcn_sched_barrier(0); }
    BARR;
  }
#undef STGA
#undef STGB
#undef DSRA2
#undef DSRBW
#undef MFMAP
#undef BARR
#undef LGK0

  float* fout = (float*)p0;
  const float* addsrc = (const float*)p1;
#pragma unroll
  for (int m = 0; m < 4; ++m) {
    long r0 = bm + wr * 64 + m * 16 + lkg * 4;
#pragma unroll
    for (int n = 0; n < 4; ++n) {
      long c = bn + wc * 64 + n * 16 + lr;
#pragma unroll
      for (int r = 0; r < 4; ++r) {
        long idx = (r0 + r) * 2048 + c;
        if (MODE == 2) fout[idx] = addsrc[idx] + acc[m][n][r];
        else fout[idx] = fout[idx] + acc[m][n][r];
      }
    }
  }
}

// ---------------------------------------------------------------- flash attention (r8 known-good)
__global__ __launch_bounds__(256, 3) void flash_attn_kernel(
    const unsigned short* __restrict__ Q, const unsigned short* __restrict__ Kb,
    const unsigned short* __restrict__ vT, unsigned short* __restrict__ O) {
  __shared__ unsigned short Ks[64 * 128];
  __shared__ unsigned short Vs[128 * 64];
  __shared__ unsigned short Ps[4][16][72];
  const int bid = (int)blockIdx.x;
  const int wg = (bid & 7) * 128 + (bid >> 3);
  const int qt = wg & 31, h = (wg >> 5) & 15, b = wg >> 9;
  const int tid = threadIdx.x, wave = tid >> 6, lane = tid & 63;
  const int lr = lane & 15, lkg = lane >> 4, lk = lkg * 8;
  const long rowbase = (long)b * SEQ;
  const int qrow0 = qt * 64 + wave * 16;
  bf16x8 aq[4];
#pragma unroll
  for (int ks = 0; ks < 4; ++ks)
    aq[ks] = *(const bf16x8*)(Q + (rowbase + qrow0 + lr) * HIDN + h * HD + ks * 32 + lk);
  const unsigned short* vbase = vT + ((long)(b * 16 + h) * 128) * SEQ;  // [d][s]
  const int kr_ = tid >> 4, kc_ = tid & 15;
  const int vd_ = tid >> 3, vc_ = tid & 7;
  int4 kreg[4], vreg[4];
  f32x4 acc[8] = {};
  float m_ = -3.0e38f, l_ = 0.f;

#define GLOADKV(kv0_)                                                              \
  { _Pragma("unroll")                                                              \
    for (int j = 0; j < 4; ++j)                                                    \
      kreg[j] = *(const int4*)(Kb + (rowbase + (kv0_) + kr_ + j * 16) * HIDN + h * HD + kc_ * 8); \
    _Pragma("unroll")                                                              \
    for (int j = 0; j < 4; ++j)                                                    \
      vreg[j] = *(const int4*)(vbase + (long)(vd_ + j * 32) * SEQ + (kv0_) + vc_ * 8); }
#define DSWRITEKV()                                                                \
  { _Pragma("unroll")                                                              \
    for (int j = 0; j < 4; ++j) {                                                  \
      int row = kr_ + j * 16;                                                      \
      *(int4*)((char*)Ks + row * 256 + ((kc_ ^ (row & 15)) << 4)) = kreg[j];       \
    }                                                                              \
    _Pragma("unroll")                                                              \
    for (int j = 0; j < 4; ++j) {                                                  \
      int d = vd_ + j * 32;                                                        \
      *(int4*)((char*)Vs + d * 128 + ((vc_ ^ (d & 7)) << 4)) = vreg[j];            \
    } }

  GLOADKV(0);
  asm volatile("s_waitcnt vmcnt(0)" ::: "memory");
  DSWRITEKV();
  asm volatile("s_waitcnt lgkmcnt(0)" ::: "memory");
  __builtin_amdgcn_sched_barrier(0);
  asm volatile("s_barrier" ::: "memory");

  for (int t = 0; t < SEQ / 64; ++t) {
    if (t + 1 < SEQ / 64) GLOADKV((long)(t + 1) * 64);
    const char* ksb = (const char*)Ks;
    f32x4 sa[4] = {};
#pragma unroll
    for (int n = 0; n < 4; ++n) {
      int row = n * 16 + lr;
#pragma unroll
      for (int ks = 0; ks < 4; ++ks) {
        bf16x8 bk = *(const bf16x8*)(ksb + row * 256 + (((ks * 4 + lkg) ^ (row & 15)) << 4));
        sa[n] = MFMA16(bk, aq[ks], sa[n]);
      }
    }
    float pmax = sa[0][0];
#pragma unroll
    for (int n = 0; n < 4; ++n)
#pragma unroll
      for (int r = 0; r < 4; ++r) pmax = fmaxf(pmax, sa[n][r]);
    pmax = fmaxf(pmax, __shfl_xor(pmax, 16));
    pmax = fmaxf(pmax, __shfl_xor(pmax, 32));
    if (__all(pmax - m_ <= 11.54f)) {
      float psum = 0.f;
#pragma unroll
      for (int n = 0; n < 4; ++n)
#pragma unroll
        for (int r = 0; r < 4; ++r) {
          float p = exp2f(sa[n][r] - m_);
          sa[n][r] = p;
          psum += p;
        }
      psum += __shfl_xor(psum, 16);
      psum += __shfl_xor(psum, 32);
      l_ += psum;
    } else {
      float mnew = fmaxf(m_, pmax);
      float corr = exp2f(m_ - mnew);
      float psum = 0.f;
#pragma unroll
      for (int n = 0; n < 4; ++n)
#pragma unroll
        for (int r = 0; r < 4; ++r) {
          float p = exp2f(sa[n][r] - mnew);
          sa[n][r] = p;
          psum += p;
        }
      psum += __shfl_xor(psum, 16);
      psum += __shfl_xor(psum, 32);
      l_ = l_ * corr + psum;
      m_ = mnew;
      float corr4[4];
#pragma unroll
      for (int r = 0; r < 4; ++r) corr4[r] = __shfl(corr, 4 * lkg + r);
#pragma unroll
      for (int df = 0; df < 8; ++df)
#pragma unroll
        for (int r = 0; r < 4; ++r) acc[df][r] *= corr4[r];
    }
#pragma unroll
    for (int n = 0; n < 4; ++n) {
      ushort4 pw;
      pw.x = f2bf(sa[n][0]); pw.y = f2bf(sa[n][1]);
      pw.z = f2bf(sa[n][2]); pw.w = f2bf(sa[n][3]);
      *(ushort4*)&Ps[wave][lr][n * 16 + 4 * lkg] = pw;
    }
    bf16x8 pa0 = *(const bf16x8*)&Ps[wave][lr][lk];
    bf16x8 pa1 = *(const bf16x8*)&Ps[wave][lr][32 + lk];
    const char* vsb = (const char*)Vs;
#pragma unroll
    for (int df = 0; df < 8; ++df) {
      int row = df * 16 + lr;
      int x7 = row & 7;
      bf16x8 bv0 = *(const bf16x8*)(vsb + row * 128 + ((lkg ^ x7) << 4));
      bf16x8 bv1 = *(const bf16x8*)(vsb + row * 128 + (((4 + lkg) ^ x7) << 4));
      acc[df] = MFMA16(pa0, bv0, acc[df]);
      acc[df] = MFMA16(pa1, bv1, acc[df]);
    }
    asm volatile("s_barrier" ::: "memory");
    if (t + 1 < SEQ / 64) {
      asm volatile("s_waitcnt vmcnt(0)" ::: "memory");
      DSWRITEKV();
      asm volatile("s_waitcnt lgkmcnt(0)" ::: "memory");
      __builtin_amdgcn_sched_barrier(0);
      asm volatile("s_barrier" ::: "memory");
    }
  }
#undef GLOADKV
#undef DSWRITEKV
  float invl = 1.0f / l_;
  float invl4[4];
#pragma unroll
  for (int r = 0; r < 4; ++r) invl4[r] = __shfl(invl, 4 * lkg + r);
#pragma unroll
  for (int r = 0; r < 4; ++r) {
    long orow = rowbase + qrow0 + lkg * 4 + r;
#pragma unroll
    for (int df = 0; df < 8; ++df)
      O[orow * HIDN + h * HD + df * 16 + lr] = f2bf(acc[df][r] * invl4[r]);
  }
}

// ---------------------------------------------------------------- launcher
extern "C" void kernel_launch(void* const* d_in, const int* in_sizes, int n_in,
                              void* d_out, int out_size, void* d_ws, size_t ws_size,
                              hipStream_t stream) {
  const float* hidden = (const float*)d_in[0];
  const float* Wq = (const float*)d_in[1];
  const float* Wk = (const float*)d_in[2];
  const float* Wv = (const float*)d_in[3];
  const float* Wo = (const float*)d_in[4];
  const float* w1 = (const float*)d_in[5];
  const float* w2 = (const float*)d_in[6];
  const float* w3 = (const float*)d_in[7];
  const float* ln1 = (const float*)d_in[8];
  const float* ln2 = (const float*)d_in[9];
  float* out = (float*)d_out;

  char* ws = (char*)d_ws;
  size_t off = 0;
  auto alloc = [&](size_t bytes) -> void* {
    void* p = ws + off;
    off += (bytes + 255) & ~(size_t)255;
    return p;
  };
  unsigned short* wblk = (unsigned short*)alloc((size_t)(2048L * 6 + 2048) * HIDN * 2);
  unsigned short* wQ = wblk;
  unsigned short* wG = wblk + (size_t)8192 * HIDN;
  unsigned short* wO = wblk + (size_t)6144 * HIDN;
  unsigned short* wD = wblk + (size_t)12288 * HIDN;
  unsigned short* xb   = (unsigned short*)alloc((size_t)NROWS * HIDN * 2);
  unsigned short* qb   = (unsigned short*)alloc((size_t)NROWS * HIDN * 2);
  unsigned short* kb   = (unsigned short*)alloc((size_t)NROWS * HIDN * 2);
  unsigned short* vTb  = (unsigned short*)alloc((size_t)NROWS * HIDN * 2);
  unsigned short* ctxb = (unsigned short*)alloc((size_t)NROWS * HIDN * 2);
  float* cosT = (float*)alloc((size_t)SEQ * 64 * 4);
  float* sinT = (float*)alloc((size_t)SEQ * 64 * 4);
  if (off > ws_size) return;

  transpose_all_kernel<<<dim3(HIDN / 64, HIDN / 64, 7), 256, 0, stream>>>(
      Wq, Wk, Wv, Wo, w1, w3, w2, wblk);
  rope_table_kernel<<<SEQ, 64, 0, stream>>>(cosT, sinT);

  rmsnorm_kernel<<<NROWS, 256, 0, stream>>>(hidden, ln1, xb);

  // QKV (N=6144) 8-phase 256^2 with rope epilogue -> qb, kb, vTb
  gemm256_kernel<0><<<(6144 / 256) * (NROWS / 256), 512, 0, stream>>>(
      xb, wQ, 6144 / 256, qb, kb, vTb, cosT, sinT);

  flash_attn_kernel<<<(SEQ / 64) * NHEAD * BATCH, 256, 0, stream>>>(qb, kb, vTb, ctxb);

  // attn_out + residual -> out (f32), 128x256 4-phase (256 blocks, 1 round)
  gemmWide_kernel<2><<<256, 512, 0, stream>>>(ctxb, wO, out, hidden);

  rmsnorm_kernel<<<NROWS, 256, 0, stream>>>(out, ln2, xb);

  // gate: silu(y@w1)*(y@w3) (N=4096 interleaved) -> qb
  gemm256_kernel<1><<<(4096 / 256) * (NROWS / 256), 512, 0, stream>>>(
      xb, wG, 4096 / 256, qb, nullptr, nullptr, nullptr, nullptr);

  // down: out += gs @ w2, 128x256 4-phase (256 blocks, 1 round)
  gemmWide_kernel<3><<<256, 512, 0, stream>>>(qb, wD, out, nullptr);
}